// Round 15
// baseline (1009.293 us; speedup 1.0000x reference)
//
#include <hip/hip_runtime.h>
#include <hip/hip_bf16.h>
#include <cmath>

#define HC 64
typedef __hip_bfloat16 bf16;
typedef unsigned int uint;
typedef float v4f __attribute__((ext_vector_type(4)));
typedef float v2f __attribute__((ext_vector_type(2)));

__device__ __forceinline__ uint pack_bf2(float a, float b) {
    __hip_bfloat162 h = __float22bfloat162_rn(make_float2(a, b));
    return *reinterpret_cast<uint*>(&h);
}
__device__ __forceinline__ float bfl(uint u) { return __uint_as_float(u << 16); }
__device__ __forceinline__ float bfh(uint u) { return __uint_as_float(u & 0xffff0000u); }

// ---------------- pass A: per-block bucket histogram -> hist[bucket][blk] ----------------

__global__ __launch_bounds__(1024) void histA_k(const int* __restrict__ dst,
                                                int* __restrict__ hist, int E, int nbk, int nblk) {
    __shared__ int lh[512];
    int t = threadIdx.x;
    for (int i = t; i < nbk; i += 1024) lh[i] = 0;
    __syncthreads();
    int base = blockIdx.x * 8192;
#pragma unroll
    for (int k = 0; k < 8; ++k) {
        int e = base + k * 1024 + t;
        if (e < E) atomicAdd(&lh[dst[e] >> 7], 1);
    }
    __syncthreads();
    for (int i = t; i < nbk; i += 1024) hist[(size_t)i * nblk + blockIdx.x] = lh[i];
}

// ---------------- pass B: parallel per-bucket row scan (block per bucket) ----------------

__global__ __launch_bounds__(256) void scanB_k(int* __restrict__ hist, int* __restrict__ btot,
                                               int nblk) {
    __shared__ int tmp[256];
    __shared__ int carry;
    int b = blockIdx.x, t = threadIdx.x;
    int* row = hist + (size_t)b * nblk;
    if (t == 0) carry = 0;
    __syncthreads();
    for (int base = 0; base < nblk; base += 256) {
        int i = base + t;
        int v = (i < nblk) ? row[i] : 0;
        tmp[t] = v;
        __syncthreads();
        for (int off = 1; off < 256; off <<= 1) {
            int a = (t >= off) ? tmp[t - off] : 0;
            __syncthreads();
            tmp[t] += a;
            __syncthreads();
        }
        if (i < nblk) row[i] = carry + tmp[t] - v;
        __syncthreads();
        if (t == 0) carry += tmp[255];
        __syncthreads();
    }
    if (t == 0) btot[b] = carry;
}

// ---------------- pass C: scan bucket totals -> bstart ----------------

__global__ __launch_bounds__(512) void scanC_k(const int* __restrict__ btot,
                                               int* __restrict__ bstart, int nbk, int E) {
    __shared__ int tmp[512];
    int t = threadIdx.x;
    int v = (t < nbk) ? btot[t] : 0;
    tmp[t] = v;
    __syncthreads();
    for (int off = 1; off < 512; off <<= 1) {
        int a = (t >= off) ? tmp[t - off] : 0;
        __syncthreads();
        tmp[t] += a;
        __syncthreads();
    }
    if (t < nbk) bstart[t] = tmp[t] - v;
    if (t == 0) bstart[nbk] = E;
}

// ---------------- pass D: scatter records using precomputed bases ----------------

__global__ __launch_bounds__(1024) void bucketC_k(
        const int* __restrict__ src, const int* __restrict__ dst,
        const float4* __restrict__ eattr, const int* __restrict__ hist,
        const int* __restrict__ bstart,
        uint* __restrict__ tsd, uint2* __restrict__ tea, int E, int nbk, int nblk) {
    __shared__ int lcnt[512];
    __shared__ int lbase[512];
    int t = threadIdx.x;
    for (int i = t; i < nbk; i += 1024) lcnt[i] = 0;
    __syncthreads();
    int base = blockIdx.x * 8192;
    int myd[8], mylp[8];
#pragma unroll
    for (int k = 0; k < 8; ++k) {
        int e = base + k * 1024 + t;
        if (e < E) {
            int d = dst[e];
            myd[k] = d;
            mylp[k] = atomicAdd(&lcnt[d >> 7], 1);
        } else myd[k] = -1;
    }
    __syncthreads();
    for (int i = t; i < nbk; i += 1024)
        lbase[i] = hist[(size_t)i * nblk + blockIdx.x] + bstart[i];
    __syncthreads();
#pragma unroll
    for (int k = 0; k < 8; ++k) {
        int e = base + k * 1024 + t;
        if (e >= E) continue;
        int d = myd[k];
        int pos = lbase[d >> 7] + mylp[k];
        tsd[pos] = (uint)src[e] | ((uint)(d & 127) << 25);
        float4 ea = eattr[e];
        tea[pos] = make_uint2(pack_bf2(ea.x, ea.y), pack_bf2(ea.z, ea.w));
    }
}

// ---------------- in-LDS counting sort per bucket -> exact CSR ----------------

__global__ __launch_bounds__(256) void bucket_sort_k(
        const uint* __restrict__ tsd, const uint2* __restrict__ tea,
        const int* __restrict__ bstart,
        uint* __restrict__ spre_sorted, uint2* __restrict__ eat_sorted,
        int* __restrict__ row_start, int n) {
    __shared__ int cnt[128], pfx[128], cur[128];
    int b = blockIdx.x, t = threadIdx.x;
    int i0 = bstart[b], i1 = bstart[b + 1];
    int node0 = b << 7;
    if (t < 128) cnt[t] = 0;
    __syncthreads();
    for (int i = i0 + t; i < i1; i += 256) atomicAdd(&cnt[tsd[i] >> 25], 1);
    __syncthreads();
    if (t < 128) pfx[t] = cnt[t];
    __syncthreads();
    for (int off = 1; off < 128; off <<= 1) {
        int a = (t < 128 && t >= off) ? pfx[t - off] : 0;
        __syncthreads();
        if (t < 128) pfx[t] += a;
        __syncthreads();
    }
    if (t < 128) {
        int ex = pfx[t] - cnt[t];
        cur[t] = ex;
        if (node0 + t <= n) row_start[node0 + t] = i0 + ex;
    }
    __syncthreads();
    for (int i = i0 + t; i < i1; i += 256) {
        uint u = tsd[i];
        int dl = (int)(u >> 25);
        int pos = i0 + atomicAdd(&cur[dl], 1);
        spre_sorted[pos] = (u & 0x1FFFFFFu) << 7;
        eat_sorted[pos] = tea[i];
    }
}

// ---------------- layer-0 linear: din=128, bf16 W in LDS, v2f packed accumulators ----------------

__global__ __launch_bounds__(256) void lin128_k(
        const float* __restrict__ x, int n,
        const float* __restrict__ Wl, const float* __restrict__ bl,
        const float* __restrict__ Wr, const float* __restrict__ br,
        bf16* __restrict__ xl, bf16* __restrict__ xr, int ngroups16) {
    __shared__ uint sWl2[64 * 64];
    __shared__ uint sWr2[64 * 64];
    __shared__ float sx[16 * 128];
    int t = threadIdx.x;
    for (int i = t; i < 64 * 64; i += 256) {
        int k2 = i >> 6, c = i & 63;
        sWl2[i] = pack_bf2(Wl[(2 * k2) * 64 + c], Wl[(2 * k2 + 1) * 64 + c]);
        sWr2[i] = pack_bf2(Wr[(2 * k2) * 64 + c], Wr[(2 * k2 + 1) * 64 + c]);
    }
    int c = t & 63, w = t >> 6;
    float blc = bl[c], brc = br[c];
    for (int gidx = blockIdx.x; gidx < ngroups16; gidx += gridDim.x) {
        int node0 = gidx * 16;
        __syncthreads();
        for (int i = t; i < 16 * 128; i += 256) {
            int r = node0 + (i >> 7);
            sx[i] = (r < n) ? x[(size_t)r * 128 + (i & 127)] : 0.f;
        }
        __syncthreads();
        v2f al0 = {0.f, 0.f}, al1 = al0, al2 = al0, al3 = al0;
        v2f ar0 = al0, ar1 = al0, ar2 = al0, ar3 = al0;
        const float* sx0 = sx + w * 4 * 128;
#pragma unroll 8
        for (int k2 = 0; k2 < 64; ++k2) {
            uint wlu = sWl2[k2 * 64 + c], wru = sWr2[k2 * 64 + c];
            v2f wl = {bfl(wlu), bfh(wlu)};
            v2f wr = {bfl(wru), bfh(wru)};
            v2f xa = *(const v2f*)&sx0[k2 * 2];
            v2f xb = *(const v2f*)&sx0[128 + k2 * 2];
            v2f xc = *(const v2f*)&sx0[256 + k2 * 2];
            v2f xd = *(const v2f*)&sx0[384 + k2 * 2];
            al0 += xa * wl; ar0 += xa * wr;
            al1 += xb * wl; ar1 += xb * wr;
            al2 += xc * wl; ar2 += xc * wr;
            al3 += xd * wl; ar3 += xd * wr;
        }
        int nb_ = node0 + w * 4;
        if (nb_ + 0 < n) { xl[(size_t)(nb_ + 0) * 64 + c] = __float2bfloat16(al0.x + al0.y + blc); xr[(size_t)(nb_ + 0) * 64 + c] = __float2bfloat16(ar0.x + ar0.y + brc); }
        if (nb_ + 1 < n) { xl[(size_t)(nb_ + 1) * 64 + c] = __float2bfloat16(al1.x + al1.y + blc); xr[(size_t)(nb_ + 1) * 64 + c] = __float2bfloat16(ar1.x + ar1.y + brc); }
        if (nb_ + 2 < n) { xl[(size_t)(nb_ + 2) * 64 + c] = __float2bfloat16(al2.x + al2.y + blc); xr[(size_t)(nb_ + 2) * 64 + c] = __float2bfloat16(ar2.x + ar2.y + brc); }
        if (nb_ + 3 < n) { xl[(size_t)(nb_ + 3) * 64 + c] = __float2bfloat16(al3.x + al3.y + blc); xr[(size_t)(nb_ + 3) * 64 + c] = __float2bfloat16(ar3.x + ar3.y + brc); }
    }
}

// ---------------- layer-1 linear: din=64, fused input BN+ELU, v2f packed ----------------

__global__ __launch_bounds__(256) void lin64bn_k(
        const float* __restrict__ x, int n,
        const float* __restrict__ sums, const float* __restrict__ sqs,
        const float* __restrict__ g, const float* __restrict__ be,
        const float* __restrict__ Wl, const float* __restrict__ bl,
        const float* __restrict__ Wr, const float* __restrict__ br,
        bf16* __restrict__ xl, bf16* __restrict__ xr, int ngroups16) {
    __shared__ uint sWl2[32 * 64];
    __shared__ uint sWr2[32 * 64];
    __shared__ float sx[16 * 64];
    __shared__ float ssc[64], ssh[64];
    int t = threadIdx.x;
    if (t < 64) {
        float inv_n = 1.f / n;
        float mu = sums[t] * inv_n;
        float var = sqs[t] * inv_n - mu * mu;
        float sc = rsqrtf(var + 1e-5f) * g[t];
        ssc[t] = sc; ssh[t] = be[t] - mu * sc;
    }
    for (int i = t; i < 32 * 64; i += 256) {
        int k2 = i >> 6, c = i & 63;
        sWl2[i] = pack_bf2(Wl[(2 * k2) * 64 + c], Wl[(2 * k2 + 1) * 64 + c]);
        sWr2[i] = pack_bf2(Wr[(2 * k2) * 64 + c], Wr[(2 * k2 + 1) * 64 + c]);
    }
    int c = t & 63, w = t >> 6;
    float blc = bl[c], brc = br[c];
    for (int gidx = blockIdx.x; gidx < ngroups16; gidx += gridDim.x) {
        int node0 = gidx * 16;
        __syncthreads();
        for (int i = t; i < 16 * 64; i += 256) {
            int r = node0 + (i >> 6);
            float v = (r < n) ? x[(size_t)r * 64 + (i & 63)] : 0.f;
            v = v * ssc[i & 63] + ssh[i & 63];
            sx[i] = v > 0.f ? v : __expf(v) - 1.f;
        }
        __syncthreads();
        v2f al0 = {0.f, 0.f}, al1 = al0, al2 = al0, al3 = al0;
        v2f ar0 = al0, ar1 = al0, ar2 = al0, ar3 = al0;
        const float* sx0 = sx + w * 4 * 64;
#pragma unroll 8
        for (int k2 = 0; k2 < 32; ++k2) {
            uint wlu = sWl2[k2 * 64 + c], wru = sWr2[k2 * 64 + c];
            v2f wl = {bfl(wlu), bfh(wlu)};
            v2f wr = {bfl(wru), bfh(wru)};
            v2f xa = *(const v2f*)&sx0[k2 * 2];
            v2f xb = *(const v2f*)&sx0[64 + k2 * 2];
            v2f xc = *(const v2f*)&sx0[128 + k2 * 2];
            v2f xd = *(const v2f*)&sx0[192 + k2 * 2];
            al0 += xa * wl; ar0 += xa * wr;
            al1 += xb * wl; ar1 += xb * wr;
            al2 += xc * wl; ar2 += xc * wr;
            al3 += xd * wl; ar3 += xd * wr;
        }
        int nb_ = node0 + w * 4;
        if (nb_ + 0 < n) { xl[(size_t)(nb_ + 0) * 64 + c] = __float2bfloat16(al0.x + al0.y + blc); xr[(size_t)(nb_ + 0) * 64 + c] = __float2bfloat16(ar0.x + ar0.y + brc); }
        if (nb_ + 1 < n) { xl[(size_t)(nb_ + 1) * 64 + c] = __float2bfloat16(al1.x + al1.y + blc); xr[(size_t)(nb_ + 1) * 64 + c] = __float2bfloat16(ar1.x + ar1.y + brc); }
        if (nb_ + 2 < n) { xl[(size_t)(nb_ + 2) * 64 + c] = __float2bfloat16(al2.x + al2.y + blc); xr[(size_t)(nb_ + 2) * 64 + c] = __float2bfloat16(ar2.x + ar2.y + brc); }
        if (nb_ + 3 < n) { xl[(size_t)(nb_ + 3) * 64 + c] = __float2bfloat16(al3.x + al3.y + blc); xr[(size_t)(nb_ + 3) * 64 + c] = __float2bfloat16(ar3.x + ar3.y + brc); }
    }
}

// ---------------- fused GAT + BN stats epilogue ----------------

__global__ __launch_bounds__(256) void gat_node_k(
        const bf16* __restrict__ xl, const bf16* __restrict__ xr,
        const float* __restrict__ We, const float* __restrict__ att,
        const int* __restrict__ row_start, const uint* __restrict__ spre,
        const uint2* __restrict__ eat,
        float* __restrict__ out, float* __restrict__ sums, float* __restrict__ sqs, int n) {
    __shared__ float lsum[64], lsq[64];
    int t = threadIdx.x;
    if (t < 64) { lsum[t] = 0.f; lsq[t] = 0.f; }
    __syncthreads();
    int lane = t & 63;
    int quad = lane >> 4;
    int c4 = lane & 15;
    int node = blockIdx.x * 4 + (t >> 6);
    bool valid = node < n;
    int nclamp = valid ? node : (n - 1);
    int c0 = c4 << 2;
    v4f w0 = {We[c0], We[c0 + 1], We[c0 + 2], We[c0 + 3]};
    v4f w1 = {We[64 + c0], We[64 + c0 + 1], We[64 + c0 + 2], We[64 + c0 + 3]};
    v4f w2 = {We[128 + c0], We[128 + c0 + 1], We[128 + c0 + 2], We[128 + c0 + 3]};
    v4f w3 = {We[192 + c0], We[192 + c0 + 1], We[192 + c0 + 2], We[192 + c0 + 3]};
    v4f ratt = {att[c0] * 1.44269504f, att[c0 + 1] * 1.44269504f,
                att[c0 + 2] * 1.44269504f, att[c0 + 3] * 1.44269504f};
    const char* xlb = (const char*)xl;
    uint2 xru = *(const uint2*)((const char*)xr + ((size_t)nclamp << 7) + ((uint)c0 << 1));
    v4f xrd = {bfl(xru.x), bfh(xru.x), bfl(xru.y), bfh(xru.y)};
    int rs = valid ? row_start[node] : 0;
    int re = valid ? row_start[node + 1] : 0;
    v4f acc = {0.f, 0.f, 0.f, 0.f};
    float srun = 0.f;
    uint coff = (uint)c4 << 3;

#define PROC(EA, XU) { \
        v4f xv = {bfl((XU).x), bfh((XU).x), bfl((XU).y), bfh((XU).y)}; \
        v4f z = xv + xrd; \
        float e0 = bfl((EA).x), e1 = bfh((EA).x); \
        float e2 = bfl((EA).y), e3 = bfh((EA).y); \
        z += e0 * w0; z += e1 * w1; z += e2 * w2; z += e3 * w3; \
        z = __builtin_elementwise_max(z, 0.2f * z); \
        v4f zr = z * ratt; \
        float v = (zr.x + zr.y) + (zr.z + zr.w); \
        v += __shfl_xor(v, 1); v += __shfl_xor(v, 2); \
        float p = exp2f(v); \
        srun += p; \
        acc += p * xv; \
    }

    int i = rs;
    for (; i + 16 <= re; i += 16) {
        uint sp0 = spre[i + quad],      sp1 = spre[i + 4 + quad];
        uint sp2 = spre[i + 8 + quad],  sp3 = spre[i + 12 + quad];
        uint2 ea0 = eat[i + quad],      ea1 = eat[i + 4 + quad];
        uint2 ea2 = eat[i + 8 + quad],  ea3 = eat[i + 12 + quad];
        uint2 xu0 = *(const uint2*)(xlb + sp0 + coff);
        uint2 xu1 = *(const uint2*)(xlb + sp1 + coff);
        uint2 xu2 = *(const uint2*)(xlb + sp2 + coff);
        uint2 xu3 = *(const uint2*)(xlb + sp3 + coff);
        PROC(ea0, xu0);
        PROC(ea1, xu1);
        PROC(ea2, xu2);
        PROC(ea3, xu3);
    }
    for (; i + 8 <= re; i += 8) {
        uint spA = spre[i + quad], spB = spre[i + 4 + quad];
        uint2 eaA = eat[i + quad], eaB = eat[i + 4 + quad];
        uint2 xuA = *(const uint2*)(xlb + spA + coff);
        uint2 xuB = *(const uint2*)(xlb + spB + coff);
        PROC(eaA, xuA);
        PROC(eaB, xuB);
    }
    for (; i < re; i += 4) {
        int ei = i + quad;
        bool ok = ei < re;
        int eic = ok ? ei : i;
        uint sp = spre[eic];
        uint2 ea = eat[eic];
        uint2 xu = *(const uint2*)(xlb + sp + coff);
        v4f xv = {bfl(xu.x), bfh(xu.x), bfl(xu.y), bfh(xu.y)};
        v4f z = xv + xrd;
        float e0 = bfl(ea.x), e1 = bfh(ea.x);
        float e2 = bfl(ea.y), e3 = bfh(ea.y);
        z += e0 * w0; z += e1 * w1; z += e2 * w2; z += e3 * w3;
        z = __builtin_elementwise_max(z, 0.2f * z);
        v4f zr = z * ratt;
        float v = (zr.x + zr.y) + (zr.z + zr.w);
        v += __shfl_xor(v, 1); v += __shfl_xor(v, 2);
        float p = ok ? exp2f(v) : 0.f;
        srun += p;
        acc += p * xv;
    }
#undef PROC

    srun += __shfl_xor(srun, 16);  srun += __shfl_xor(srun, 32);
    acc.x += __shfl_xor(acc.x, 16); acc.x += __shfl_xor(acc.x, 32);
    acc.y += __shfl_xor(acc.y, 16); acc.y += __shfl_xor(acc.y, 32);
    acc.z += __shfl_xor(acc.z, 16); acc.z += __shfl_xor(acc.z, 32);
    acc.w += __shfl_xor(acc.w, 16); acc.w += __shfl_xor(acc.w, 32);
    if (valid && quad == 0) {
        float inv = 1.f / (srun + 1e-16f);
        v4f o = acc * inv;
        *(v4f*)&out[((size_t)node << 6) + (uint)c0] = o;
        atomicAdd(&lsum[c0 + 0], o.x); atomicAdd(&lsq[c0 + 0], o.x * o.x);
        atomicAdd(&lsum[c0 + 1], o.y); atomicAdd(&lsq[c0 + 1], o.y * o.y);
        atomicAdd(&lsum[c0 + 2], o.z); atomicAdd(&lsq[c0 + 2], o.z * o.z);
        atomicAdd(&lsum[c0 + 3], o.w); atomicAdd(&lsq[c0 + 3], o.w * o.w);
    }
    __syncthreads();
    if (t < 64) {
        atomicAdd(&sums[t], lsum[t]);
        atomicAdd(&sqs[t], lsq[t]);
    }
}

// ---------------- head fc 64->64 (fused input BN+ELU, fused output stats, v2f packed) ----------------

__global__ __launch_bounds__(256) void lin1_k(
        const float* __restrict__ x, int n,
        const float* __restrict__ sums, const float* __restrict__ sqs,
        const float* __restrict__ g, const float* __restrict__ be,
        const float* __restrict__ W, const float* __restrict__ b,
        float* __restrict__ y, float* __restrict__ sums_o, float* __restrict__ sqs_o,
        int ngroups16) {
    __shared__ uint sW2[32 * 64];
    __shared__ float sx[16 * 64];
    __shared__ float ssc[64], ssh[64];
    __shared__ float ls[256], lq[256];
    int t = threadIdx.x;
    if (t < 64) {
        float inv_n = 1.f / n;
        float mu = sums[t] * inv_n;
        float var = sqs[t] * inv_n - mu * mu;
        float sc = rsqrtf(var + 1e-5f) * g[t];
        ssc[t] = sc; ssh[t] = be[t] - mu * sc;
    }
    for (int i = t; i < 32 * 64; i += 256) {
        int k2 = i >> 6, c = i & 63;
        sW2[i] = pack_bf2(W[(2 * k2) * 64 + c], W[(2 * k2 + 1) * 64 + c]);
    }
    int c = t & 63, w = t >> 6;
    float bc = b[c];
    float s = 0.f, q = 0.f;
    for (int gidx = blockIdx.x; gidx < ngroups16; gidx += gridDim.x) {
        int node0 = gidx * 16;
        __syncthreads();
        for (int i = t; i < 16 * 64; i += 256) {
            int r = node0 + (i >> 6);
            float v = (r < n) ? x[(size_t)r * 64 + (i & 63)] : 0.f;
            v = v * ssc[i & 63] + ssh[i & 63];
            sx[i] = v > 0.f ? v : __expf(v) - 1.f;
        }
        __syncthreads();
        v2f a0 = {0.f, 0.f}, a1 = a0, a2 = a0, a3 = a0;
        const float* sx0 = sx + w * 4 * 64;
#pragma unroll 8
        for (int k2 = 0; k2 < 32; ++k2) {
            uint wu = sW2[k2 * 64 + c];
            v2f wv = {bfl(wu), bfh(wu)};
            v2f xa = *(const v2f*)&sx0[k2 * 2];
            v2f xb = *(const v2f*)&sx0[64 + k2 * 2];
            v2f xc = *(const v2f*)&sx0[128 + k2 * 2];
            v2f xd = *(const v2f*)&sx0[192 + k2 * 2];
            a0 += xa * wv;
            a1 += xb * wv;
            a2 += xc * wv;
            a3 += xd * wv;
        }
        int nb_ = node0 + w * 4;
        float o0 = a0.x + a0.y + bc, o1 = a1.x + a1.y + bc;
        float o2 = a2.x + a2.y + bc, o3 = a3.x + a3.y + bc;
        if (nb_ + 0 < n) { y[(size_t)(nb_ + 0) * 64 + c] = o0; s += o0; q = fmaf(o0, o0, q); }
        if (nb_ + 1 < n) { y[(size_t)(nb_ + 1) * 64 + c] = o1; s += o1; q = fmaf(o1, o1, q); }
        if (nb_ + 2 < n) { y[(size_t)(nb_ + 2) * 64 + c] = o2; s += o2; q = fmaf(o2, o2, q); }
        if (nb_ + 3 < n) { y[(size_t)(nb_ + 3) * 64 + c] = o3; s += o3; q = fmaf(o3, o3, q); }
    }
    __syncthreads();
    ls[t] = s; lq[t] = q;
    __syncthreads();
    if (t < 64) {
        float ss = ls[t] + ls[t + 64] + ls[t + 128] + ls[t + 192];
        float qq = lq[t] + lq[t + 64] + lq[t + 128] + lq[t + 192];
        atomicAdd(&sums_o[t], ss);
        atomicAdd(&sqs_o[t], qq);
    }
}

// ---------------- final: fused BN+ELU + dot(64) + 5*tanh ----------------

__global__ void final_k(const float* __restrict__ z, int n,
                        const float* __restrict__ sums, const float* __restrict__ sqs,
                        const float* __restrict__ g, const float* __restrict__ be,
                        const float* __restrict__ W2, const float* __restrict__ b2,
                        float* __restrict__ out) {
    int t = blockIdx.x * blockDim.x + threadIdx.x;
    int node = t >> 6, c = t & 63;
    if (node >= n) return;
    float inv_n = 1.f / n;
    float mu = sums[c] * inv_n;
    float var = sqs[c] * inv_n - mu * mu;
    float scc = rsqrtf(var + 1e-5f) * g[c];
    float sh = be[c] - mu * scc;
    float v = z[(size_t)node * 64 + c] * scc + sh;
    v = v > 0.f ? v : __expf(v) - 1.f;
    v *= W2[c];
    v += __shfl_xor(v, 1);
    v += __shfl_xor(v, 2);
    v += __shfl_xor(v, 4);
    v += __shfl_xor(v, 8);
    v += __shfl_xor(v, 16);
    v += __shfl_xor(v, 32);
    if (c == 0) out[node] = 5.0f * tanhf(v + b2[0]);
}

// ---------------- launch ----------------

extern "C" void kernel_launch(void* const* d_in, const int* in_sizes, int n_in,
                              void* d_out, int out_size, void* d_ws, size_t ws_size,
                              hipStream_t stream) {
    const float* x0    = (const float*)d_in[0];
    const int*   eidx  = (const int*)d_in[1];
    const float* eattr = (const float*)d_in[2];

    const float* Wl[2]; const float* bl[2]; const float* Wr[2]; const float* br[2];
    const float* We[2]; const float* att[2]; const float* g[2]; const float* be[2];
    for (int l = 0; l < 2; ++l) {
        int base = 3 + l * 9;
        Wl[l]  = (const float*)d_in[base + 0];
        bl[l]  = (const float*)d_in[base + 1];
        Wr[l]  = (const float*)d_in[base + 2];
        br[l]  = (const float*)d_in[base + 3];
        We[l]  = (const float*)d_in[base + 4];
        att[l] = (const float*)d_in[base + 5];
        // base+6 = bias: per-channel constant, cancels exactly under BatchNorm
        g[l]   = (const float*)d_in[base + 7];
        be[l]  = (const float*)d_in[base + 8];
    }
    const float* W1 = (const float*)d_in[21];
    const float* b1 = (const float*)d_in[22];
    const float* gf = (const float*)d_in[23];
    const float* bf = (const float*)d_in[24];
    const float* W2 = (const float*)d_in[25];
    const float* b2 = (const float*)d_in[26];

    const int N = in_sizes[0] / 128;
    const int E = in_sizes[1] / 2;
    const int* src = eidx;
    const int* dst = eidx + E;
    const int nbk = (N + 127) >> 7;
    const int nblkA = (E + 8191) / 8192;

    // workspace (4-byte units).  Region A shared: (tea,tsd) then (h0,h1).
    float* ws = (float*)d_ws;
    size_t o = 0;
    float* regionA = ws + o; o += (size_t)2 * N * HC;
    uint2* tea = (uint2*)regionA;
    uint*  tsd = (uint*)(regionA + (size_t)2 * E);
    float* h0  = regionA;
    float* h1  = regionA + (size_t)N * HC;
    uint2* eat_sorted = (uint2*)(ws + o); o += (size_t)E * 2;
    uint*  spre_sorted = (uint*)(ws + o);  o += (size_t)E;
    bf16*  xl  = (bf16*)(ws + o);  o += (size_t)N * 32;
    bf16*  xr  = (bf16*)(ws + o);  o += (size_t)N * 32;
    int*   row_start = (int*)(ws + o); o += (size_t)N + 1;
    int*   hist   = (int*)(ws + o); o += (size_t)nbk * nblkA + 64;
    float* stats  = ws + o; o += 6 * HC;
    int*   bstart = (int*)(ws + o); o += 513;
    int*   btot   = (int*)(ws + o); o += 512;
    float* s0 = stats,        *q0 = stats + 64;
    float* s1 = stats + 128,  *q1 = stats + 192;
    float* sf = stats + 256,  *qf = stats + 320;

    const int ngroups4  = (N + 3) / 4;
    const int ngroups16 = (N + 15) / 16;
    const int lin_grid = ngroups16 < 1024 ? ngroups16 : 1024;

    hipMemsetAsync(stats, 0, 6 * HC * 4, stream);

    // CSR build: atomic-free 3-pass radix with parallel scans (shared by both layers)
    histA_k<<<nblkA, 1024, 0, stream>>>(dst, hist, E, nbk, nblkA);
    scanB_k<<<nbk, 256, 0, stream>>>(hist, btot, nblkA);
    scanC_k<<<1, 512, 0, stream>>>(btot, bstart, nbk, E);
    bucketC_k<<<nblkA, 1024, 0, stream>>>(src, dst, (const float4*)eattr, hist, bstart,
                                          tsd, tea, E, nbk, nblkA);
    bucket_sort_k<<<nbk, 256, 0, stream>>>(tsd, tea, bstart, spre_sorted, eat_sorted,
                                           row_start, N);

    // layer 0  (gat epilogue computes BN stats)
    lin128_k<<<lin_grid, 256, 0, stream>>>(x0, N, Wl[0], bl[0], Wr[0], br[0], xl, xr, ngroups16);
    gat_node_k<<<ngroups4, 256, 0, stream>>>(xl, xr, We[0], att[0], row_start,
                                             spre_sorted, eat_sorted, h0, s0, q0, N);

    // layer 1 (input BN+ELU fused)
    lin64bn_k<<<lin_grid, 256, 0, stream>>>(h0, N, s0, q0, g[0], be[0],
                                            Wl[1], bl[1], Wr[1], br[1], xl, xr, ngroups16);
    gat_node_k<<<ngroups4, 256, 0, stream>>>(xl, xr, We[1], att[1], row_start,
                                             spre_sorted, eat_sorted, h1, s1, q1, N);

    // head
    float* y = h0;  // h0 dead after lin64bn
    lin1_k<<<lin_grid, 256, 0, stream>>>(h1, N, s1, q1, g[1], be[1], W1, b1, y, sf, qf, ngroups16);
    final_k<<<(int)(((size_t)N * 64 + 255) / 256), 256, 0, stream>>>(
        y, N, sf, qf, gf, bf, W2, b2, (float*)d_out);
}

// Round 16
// 344.355 us; speedup vs baseline: 2.9310x; 2.9310x over previous
//
#include <hip/hip_runtime.h>
#include <hip/hip_bf16.h>
#include <cmath>

#define HC 64
typedef __hip_bfloat16 bf16;
typedef unsigned int uint;
typedef float v4f __attribute__((ext_vector_type(4)));
typedef float v2f __attribute__((ext_vector_type(2)));

__device__ __forceinline__ uint pack_bf2(float a, float b) {
    __hip_bfloat162 h = __float22bfloat162_rn(make_float2(a, b));
    return *reinterpret_cast<uint*>(&h);
}
__device__ __forceinline__ float bfl(uint u) { return __uint_as_float(u << 16); }
__device__ __forceinline__ float bfh(uint u) { return __uint_as_float(u & 0xffff0000u); }

// ---------------- pass A: per-block bucket histogram -> hist[bucket][blk] ----------------

__global__ __launch_bounds__(1024) void histA_k(const int* __restrict__ dst,
                                                int* __restrict__ hist, int E, int nbk, int nblk) {
    __shared__ int lh[512];
    int t = threadIdx.x;
    for (int i = t; i < nbk; i += 1024) lh[i] = 0;
    __syncthreads();
    int base = blockIdx.x * 8192;
#pragma unroll
    for (int k = 0; k < 8; ++k) {
        int e = base + k * 1024 + t;
        if (e < E) atomicAdd(&lh[dst[e] >> 7], 1);
    }
    __syncthreads();
    for (int i = t; i < nbk; i += 1024) hist[(size_t)i * nblk + blockIdx.x] = lh[i];
}

// ---------------- pass B: parallel per-bucket row scan (block per bucket) ----------------

__global__ __launch_bounds__(256) void scanB_k(int* __restrict__ hist, int* __restrict__ btot,
                                               int nblk) {
    __shared__ int tmp[256];
    __shared__ int carry;
    int b = blockIdx.x, t = threadIdx.x;
    int* row = hist + (size_t)b * nblk;
    if (t == 0) carry = 0;
    __syncthreads();
    for (int base = 0; base < nblk; base += 256) {
        int i = base + t;
        int v = (i < nblk) ? row[i] : 0;
        tmp[t] = v;
        __syncthreads();
        for (int off = 1; off < 256; off <<= 1) {
            int a = (t >= off) ? tmp[t - off] : 0;
            __syncthreads();
            tmp[t] += a;
            __syncthreads();
        }
        if (i < nblk) row[i] = carry + tmp[t] - v;
        __syncthreads();
        if (t == 0) carry += tmp[255];
        __syncthreads();
    }
    if (t == 0) btot[b] = carry;
}

// ---------------- pass C: scan bucket totals -> bstart ----------------

__global__ __launch_bounds__(512) void scanC_k(const int* __restrict__ btot,
                                               int* __restrict__ bstart, int nbk, int E) {
    __shared__ int tmp[512];
    int t = threadIdx.x;
    int v = (t < nbk) ? btot[t] : 0;
    tmp[t] = v;
    __syncthreads();
    for (int off = 1; off < 512; off <<= 1) {
        int a = (t >= off) ? tmp[t - off] : 0;
        __syncthreads();
        tmp[t] += a;
        __syncthreads();
    }
    if (t < nbk) bstart[t] = tmp[t] - v;
    if (t == 0) bstart[nbk] = E;
}

// ---------------- pass D: scatter records using precomputed bases ----------------

__global__ __launch_bounds__(1024) void bucketC_k(
        const int* __restrict__ src, const int* __restrict__ dst,
        const float4* __restrict__ eattr, const int* __restrict__ hist,
        const int* __restrict__ bstart,
        uint* __restrict__ tsd, uint2* __restrict__ tea, int E, int nbk, int nblk) {
    __shared__ int lcnt[512];
    __shared__ int lbase[512];
    int t = threadIdx.x;
    for (int i = t; i < nbk; i += 1024) lcnt[i] = 0;
    __syncthreads();
    int base = blockIdx.x * 8192;
    int myd[8], mylp[8];
#pragma unroll
    for (int k = 0; k < 8; ++k) {
        int e = base + k * 1024 + t;
        if (e < E) {
            int d = dst[e];
            myd[k] = d;
            mylp[k] = atomicAdd(&lcnt[d >> 7], 1);
        } else myd[k] = -1;
    }
    __syncthreads();
    for (int i = t; i < nbk; i += 1024)
        lbase[i] = hist[(size_t)i * nblk + blockIdx.x] + bstart[i];
    __syncthreads();
#pragma unroll
    for (int k = 0; k < 8; ++k) {
        int e = base + k * 1024 + t;
        if (e >= E) continue;
        int d = myd[k];
        int pos = lbase[d >> 7] + mylp[k];
        tsd[pos] = (uint)src[e] | ((uint)(d & 127) << 25);
        float4 ea = eattr[e];
        tea[pos] = make_uint2(pack_bf2(ea.x, ea.y), pack_bf2(ea.z, ea.w));
    }
}

// ---------------- in-LDS counting sort per bucket -> exact CSR ----------------

__global__ __launch_bounds__(256) void bucket_sort_k(
        const uint* __restrict__ tsd, const uint2* __restrict__ tea,
        const int* __restrict__ bstart,
        uint* __restrict__ spre_sorted, uint2* __restrict__ eat_sorted,
        int* __restrict__ row_start, int n) {
    __shared__ int cnt[128], pfx[128], cur[128];
    int b = blockIdx.x, t = threadIdx.x;
    int i0 = bstart[b], i1 = bstart[b + 1];
    int node0 = b << 7;
    if (t < 128) cnt[t] = 0;
    __syncthreads();
    for (int i = i0 + t; i < i1; i += 256) atomicAdd(&cnt[tsd[i] >> 25], 1);
    __syncthreads();
    if (t < 128) pfx[t] = cnt[t];
    __syncthreads();
    for (int off = 1; off < 128; off <<= 1) {
        int a = (t < 128 && t >= off) ? pfx[t - off] : 0;
        __syncthreads();
        if (t < 128) pfx[t] += a;
        __syncthreads();
    }
    if (t < 128) {
        int ex = pfx[t] - cnt[t];
        cur[t] = ex;
        if (node0 + t <= n) row_start[node0 + t] = i0 + ex;
    }
    __syncthreads();
    for (int i = i0 + t; i < i1; i += 256) {
        uint u = tsd[i];
        int dl = (int)(u >> 25);
        int pos = i0 + atomicAdd(&cur[dl], 1);
        spre_sorted[pos] = (u & 0x1FFFFFFu) << 7;
        eat_sorted[pos] = tea[i];
    }
}

// ---------------- layer-0 linear: din=128, bf16 W in LDS, v2f packed accumulators ----------------

__global__ __launch_bounds__(256) void lin128_k(
        const float* __restrict__ x, int n,
        const float* __restrict__ Wl, const float* __restrict__ bl,
        const float* __restrict__ Wr, const float* __restrict__ br,
        bf16* __restrict__ xl, bf16* __restrict__ xr, int ngroups16) {
    __shared__ uint sWl2[64 * 64];
    __shared__ uint sWr2[64 * 64];
    __shared__ float sx[16 * 128];
    int t = threadIdx.x;
    for (int i = t; i < 64 * 64; i += 256) {
        int k2 = i >> 6, c = i & 63;
        sWl2[i] = pack_bf2(Wl[(2 * k2) * 64 + c], Wl[(2 * k2 + 1) * 64 + c]);
        sWr2[i] = pack_bf2(Wr[(2 * k2) * 64 + c], Wr[(2 * k2 + 1) * 64 + c]);
    }
    int c = t & 63, w = t >> 6;
    float blc = bl[c], brc = br[c];
    for (int gidx = blockIdx.x; gidx < ngroups16; gidx += gridDim.x) {
        int node0 = gidx * 16;
        __syncthreads();
        for (int i = t; i < 16 * 128; i += 256) {
            int r = node0 + (i >> 7);
            sx[i] = (r < n) ? x[(size_t)r * 128 + (i & 127)] : 0.f;
        }
        __syncthreads();
        v2f al0 = {0.f, 0.f}, al1 = al0, al2 = al0, al3 = al0;
        v2f ar0 = al0, ar1 = al0, ar2 = al0, ar3 = al0;
        const float* sx0 = sx + w * 4 * 128;
#pragma unroll 8
        for (int k2 = 0; k2 < 64; ++k2) {
            uint wlu = sWl2[k2 * 64 + c], wru = sWr2[k2 * 64 + c];
            v2f wl = {bfl(wlu), bfh(wlu)};
            v2f wr = {bfl(wru), bfh(wru)};
            v2f xa = *(const v2f*)&sx0[k2 * 2];
            v2f xb = *(const v2f*)&sx0[128 + k2 * 2];
            v2f xc = *(const v2f*)&sx0[256 + k2 * 2];
            v2f xd = *(const v2f*)&sx0[384 + k2 * 2];
            al0 += xa * wl; ar0 += xa * wr;
            al1 += xb * wl; ar1 += xb * wr;
            al2 += xc * wl; ar2 += xc * wr;
            al3 += xd * wl; ar3 += xd * wr;
        }
        int nb_ = node0 + w * 4;
        if (nb_ + 0 < n) { xl[(size_t)(nb_ + 0) * 64 + c] = __float2bfloat16(al0.x + al0.y + blc); xr[(size_t)(nb_ + 0) * 64 + c] = __float2bfloat16(ar0.x + ar0.y + brc); }
        if (nb_ + 1 < n) { xl[(size_t)(nb_ + 1) * 64 + c] = __float2bfloat16(al1.x + al1.y + blc); xr[(size_t)(nb_ + 1) * 64 + c] = __float2bfloat16(ar1.x + ar1.y + brc); }
        if (nb_ + 2 < n) { xl[(size_t)(nb_ + 2) * 64 + c] = __float2bfloat16(al2.x + al2.y + blc); xr[(size_t)(nb_ + 2) * 64 + c] = __float2bfloat16(ar2.x + ar2.y + brc); }
        if (nb_ + 3 < n) { xl[(size_t)(nb_ + 3) * 64 + c] = __float2bfloat16(al3.x + al3.y + blc); xr[(size_t)(nb_ + 3) * 64 + c] = __float2bfloat16(ar3.x + ar3.y + brc); }
    }
}

// ---------------- layer-1 linear: din=64, fused input BN+ELU, v2f packed ----------------

__global__ __launch_bounds__(256) void lin64bn_k(
        const float* __restrict__ x, int n,
        const float* __restrict__ sums, const float* __restrict__ sqs,
        const float* __restrict__ g, const float* __restrict__ be,
        const float* __restrict__ Wl, const float* __restrict__ bl,
        const float* __restrict__ Wr, const float* __restrict__ br,
        bf16* __restrict__ xl, bf16* __restrict__ xr, int ngroups16) {
    __shared__ uint sWl2[32 * 64];
    __shared__ uint sWr2[32 * 64];
    __shared__ float sx[16 * 64];
    __shared__ float ssc[64], ssh[64];
    int t = threadIdx.x;
    if (t < 64) {
        float inv_n = 1.f / n;
        float mu = sums[t] * inv_n;
        float var = sqs[t] * inv_n - mu * mu;
        float sc = rsqrtf(var + 1e-5f) * g[t];
        ssc[t] = sc; ssh[t] = be[t] - mu * sc;
    }
    for (int i = t; i < 32 * 64; i += 256) {
        int k2 = i >> 6, c = i & 63;
        sWl2[i] = pack_bf2(Wl[(2 * k2) * 64 + c], Wl[(2 * k2 + 1) * 64 + c]);
        sWr2[i] = pack_bf2(Wr[(2 * k2) * 64 + c], Wr[(2 * k2 + 1) * 64 + c]);
    }
    int c = t & 63, w = t >> 6;
    float blc = bl[c], brc = br[c];
    for (int gidx = blockIdx.x; gidx < ngroups16; gidx += gridDim.x) {
        int node0 = gidx * 16;
        __syncthreads();
        for (int i = t; i < 16 * 64; i += 256) {
            int r = node0 + (i >> 6);
            float v = (r < n) ? x[(size_t)r * 64 + (i & 63)] : 0.f;
            v = v * ssc[i & 63] + ssh[i & 63];
            sx[i] = v > 0.f ? v : __expf(v) - 1.f;
        }
        __syncthreads();
        v2f al0 = {0.f, 0.f}, al1 = al0, al2 = al0, al3 = al0;
        v2f ar0 = al0, ar1 = al0, ar2 = al0, ar3 = al0;
        const float* sx0 = sx + w * 4 * 64;
#pragma unroll 8
        for (int k2 = 0; k2 < 32; ++k2) {
            uint wlu = sWl2[k2 * 64 + c], wru = sWr2[k2 * 64 + c];
            v2f wl = {bfl(wlu), bfh(wlu)};
            v2f wr = {bfl(wru), bfh(wru)};
            v2f xa = *(const v2f*)&sx0[k2 * 2];
            v2f xb = *(const v2f*)&sx0[64 + k2 * 2];
            v2f xc = *(const v2f*)&sx0[128 + k2 * 2];
            v2f xd = *(const v2f*)&sx0[192 + k2 * 2];
            al0 += xa * wl; ar0 += xa * wr;
            al1 += xb * wl; ar1 += xb * wr;
            al2 += xc * wl; ar2 += xc * wr;
            al3 += xd * wl; ar3 += xd * wr;
        }
        int nb_ = node0 + w * 4;
        if (nb_ + 0 < n) { xl[(size_t)(nb_ + 0) * 64 + c] = __float2bfloat16(al0.x + al0.y + blc); xr[(size_t)(nb_ + 0) * 64 + c] = __float2bfloat16(ar0.x + ar0.y + brc); }
        if (nb_ + 1 < n) { xl[(size_t)(nb_ + 1) * 64 + c] = __float2bfloat16(al1.x + al1.y + blc); xr[(size_t)(nb_ + 1) * 64 + c] = __float2bfloat16(ar1.x + ar1.y + brc); }
        if (nb_ + 2 < n) { xl[(size_t)(nb_ + 2) * 64 + c] = __float2bfloat16(al2.x + al2.y + blc); xr[(size_t)(nb_ + 2) * 64 + c] = __float2bfloat16(ar2.x + ar2.y + brc); }
        if (nb_ + 3 < n) { xl[(size_t)(nb_ + 3) * 64 + c] = __float2bfloat16(al3.x + al3.y + blc); xr[(size_t)(nb_ + 3) * 64 + c] = __float2bfloat16(ar3.x + ar3.y + brc); }
    }
}

// ---------------- fused GAT: wave per node, 4 ch/lane, 4 edges/wave, 4-deep MLP ----------------

__global__ __launch_bounds__(256) void gat_node_k(
        const bf16* __restrict__ xl, const bf16* __restrict__ xr,
        const float* __restrict__ We, const float* __restrict__ att,
        const int* __restrict__ row_start, const uint* __restrict__ spre,
        const uint2* __restrict__ eat,
        float* __restrict__ out, int n) {
    int t = threadIdx.x;
    int lane = t & 63;
    int quad = lane >> 4;
    int c4 = lane & 15;
    int node = blockIdx.x * 4 + (t >> 6);
    if (node >= n) return;
    int c0 = c4 << 2;
    v4f w0 = {We[c0], We[c0 + 1], We[c0 + 2], We[c0 + 3]};
    v4f w1 = {We[64 + c0], We[64 + c0 + 1], We[64 + c0 + 2], We[64 + c0 + 3]};
    v4f w2 = {We[128 + c0], We[128 + c0 + 1], We[128 + c0 + 2], We[128 + c0 + 3]};
    v4f w3 = {We[192 + c0], We[192 + c0 + 1], We[192 + c0 + 2], We[192 + c0 + 3]};
    v4f ratt = {att[c0] * 1.44269504f, att[c0 + 1] * 1.44269504f,
                att[c0 + 2] * 1.44269504f, att[c0 + 3] * 1.44269504f};
    const char* xlb = (const char*)xl;
    uint2 xru = *(const uint2*)((const char*)xr + ((size_t)node << 7) + ((uint)c0 << 1));
    v4f xrd = {bfl(xru.x), bfh(xru.x), bfl(xru.y), bfh(xru.y)};
    int rs = row_start[node], re = row_start[node + 1];
    v4f acc = {0.f, 0.f, 0.f, 0.f};
    float srun = 0.f;
    uint coff = (uint)c4 << 3;

#define PROC(EA, XU) { \
        v4f xv = {bfl((XU).x), bfh((XU).x), bfl((XU).y), bfh((XU).y)}; \
        v4f z = xv + xrd; \
        float e0 = bfl((EA).x), e1 = bfh((EA).x); \
        float e2 = bfl((EA).y), e3 = bfh((EA).y); \
        z += e0 * w0; z += e1 * w1; z += e2 * w2; z += e3 * w3; \
        z = __builtin_elementwise_max(z, 0.2f * z); \
        v4f zr = z * ratt; \
        float v = (zr.x + zr.y) + (zr.z + zr.w); \
        v += __shfl_xor(v, 1); v += __shfl_xor(v, 2); \
        float p = exp2f(v); \
        srun += p; \
        acc += p * xv; \
    }

    int i = rs;
    for (; i + 16 <= re; i += 16) {
        uint sp0 = spre[i + quad],      sp1 = spre[i + 4 + quad];
        uint sp2 = spre[i + 8 + quad],  sp3 = spre[i + 12 + quad];
        uint2 ea0 = eat[i + quad],      ea1 = eat[i + 4 + quad];
        uint2 ea2 = eat[i + 8 + quad],  ea3 = eat[i + 12 + quad];
        uint2 xu0 = *(const uint2*)(xlb + sp0 + coff);
        uint2 xu1 = *(const uint2*)(xlb + sp1 + coff);
        uint2 xu2 = *(const uint2*)(xlb + sp2 + coff);
        uint2 xu3 = *(const uint2*)(xlb + sp3 + coff);
        PROC(ea0, xu0);
        PROC(ea1, xu1);
        PROC(ea2, xu2);
        PROC(ea3, xu3);
    }
    for (; i + 8 <= re; i += 8) {
        uint spA = spre[i + quad], spB = spre[i + 4 + quad];
        uint2 eaA = eat[i + quad], eaB = eat[i + 4 + quad];
        uint2 xuA = *(const uint2*)(xlb + spA + coff);
        uint2 xuB = *(const uint2*)(xlb + spB + coff);
        PROC(eaA, xuA);
        PROC(eaB, xuB);
    }
    for (; i < re; i += 4) {
        int ei = i + quad;
        bool ok = ei < re;
        int eic = ok ? ei : i;
        uint sp = spre[eic];
        uint2 ea = eat[eic];
        uint2 xu = *(const uint2*)(xlb + sp + coff);
        v4f xv = {bfl(xu.x), bfh(xu.x), bfl(xu.y), bfh(xu.y)};
        v4f z = xv + xrd;
        float e0 = bfl(ea.x), e1 = bfh(ea.x);
        float e2 = bfl(ea.y), e3 = bfh(ea.y);
        z += e0 * w0; z += e1 * w1; z += e2 * w2; z += e3 * w3;
        z = __builtin_elementwise_max(z, 0.2f * z);
        v4f zr = z * ratt;
        float v = (zr.x + zr.y) + (zr.z + zr.w);
        v += __shfl_xor(v, 1); v += __shfl_xor(v, 2);
        float p = ok ? exp2f(v) : 0.f;
        srun += p;
        acc += p * xv;
    }
#undef PROC

    srun += __shfl_xor(srun, 16);  srun += __shfl_xor(srun, 32);
    acc.x += __shfl_xor(acc.x, 16); acc.x += __shfl_xor(acc.x, 32);
    acc.y += __shfl_xor(acc.y, 16); acc.y += __shfl_xor(acc.y, 32);
    acc.z += __shfl_xor(acc.z, 16); acc.z += __shfl_xor(acc.z, 32);
    acc.w += __shfl_xor(acc.w, 16); acc.w += __shfl_xor(acc.w, 32);
    if (quad == 0) {
        float inv = 1.f / (srun + 1e-16f);
        v4f o = acc * inv;
        *(v4f*)&out[((size_t)node << 6) + (uint)c0] = o;
    }
}

// ---------------- BN stats (256 blocks -> low atomic contention) ----------------

__global__ void bn_stats_k(const float* __restrict__ x, float* __restrict__ sums,
                           float* __restrict__ sqs, int n) {
    __shared__ float ls[256], lq[256];
    int t = threadIdx.x;
    int c = t & 63, sub = t >> 6;
    float s = 0.f, q = 0.f;
    for (int r = blockIdx.x * 4 + sub; r < n; r += gridDim.x * 4) {
        float v = x[(size_t)r * 64 + c];
        s += v;
        q = fmaf(v, v, q);
    }
    ls[t] = s; lq[t] = q;
    __syncthreads();
    if (t < 128) { ls[t] += ls[t + 128]; lq[t] += lq[t + 128]; }
    __syncthreads();
    if (t < 64) {
        atomicAdd(&sums[c], ls[t] + ls[t + 64]);
        atomicAdd(&sqs[c], lq[t] + lq[t + 64]);
    }
}

// ---------------- head fc 64->64 (fused input BN+ELU, fused output stats, v2f packed) ----------------

__global__ __launch_bounds__(256) void lin1_k(
        const float* __restrict__ x, int n,
        const float* __restrict__ sums, const float* __restrict__ sqs,
        const float* __restrict__ g, const float* __restrict__ be,
        const float* __restrict__ W, const float* __restrict__ b,
        float* __restrict__ y, float* __restrict__ sums_o, float* __restrict__ sqs_o,
        int ngroups16) {
    __shared__ uint sW2[32 * 64];
    __shared__ float sx[16 * 64];
    __shared__ float ssc[64], ssh[64];
    __shared__ float ls[256], lq[256];
    int t = threadIdx.x;
    if (t < 64) {
        float inv_n = 1.f / n;
        float mu = sums[t] * inv_n;
        float var = sqs[t] * inv_n - mu * mu;
        float sc = rsqrtf(var + 1e-5f) * g[t];
        ssc[t] = sc; ssh[t] = be[t] - mu * sc;
    }
    for (int i = t; i < 32 * 64; i += 256) {
        int k2 = i >> 6, c = i & 63;
        sW2[i] = pack_bf2(W[(2 * k2) * 64 + c], W[(2 * k2 + 1) * 64 + c]);
    }
    int c = t & 63, w = t >> 6;
    float bc = b[c];
    float s = 0.f, q = 0.f;
    for (int gidx = blockIdx.x; gidx < ngroups16; gidx += gridDim.x) {
        int node0 = gidx * 16;
        __syncthreads();
        for (int i = t; i < 16 * 64; i += 256) {
            int r = node0 + (i >> 6);
            float v = (r < n) ? x[(size_t)r * 64 + (i & 63)] : 0.f;
            v = v * ssc[i & 63] + ssh[i & 63];
            sx[i] = v > 0.f ? v : __expf(v) - 1.f;
        }
        __syncthreads();
        v2f a0 = {0.f, 0.f}, a1 = a0, a2 = a0, a3 = a0;
        const float* sx0 = sx + w * 4 * 64;
#pragma unroll 8
        for (int k2 = 0; k2 < 32; ++k2) {
            uint wu = sW2[k2 * 64 + c];
            v2f wv = {bfl(wu), bfh(wu)};
            v2f xa = *(const v2f*)&sx0[k2 * 2];
            v2f xb = *(const v2f*)&sx0[64 + k2 * 2];
            v2f xc = *(const v2f*)&sx0[128 + k2 * 2];
            v2f xd = *(const v2f*)&sx0[192 + k2 * 2];
            a0 += xa * wv;
            a1 += xb * wv;
            a2 += xc * wv;
            a3 += xd * wv;
        }
        int nb_ = node0 + w * 4;
        float o0 = a0.x + a0.y + bc, o1 = a1.x + a1.y + bc;
        float o2 = a2.x + a2.y + bc, o3 = a3.x + a3.y + bc;
        if (nb_ + 0 < n) { y[(size_t)(nb_ + 0) * 64 + c] = o0; s += o0; q = fmaf(o0, o0, q); }
        if (nb_ + 1 < n) { y[(size_t)(nb_ + 1) * 64 + c] = o1; s += o1; q = fmaf(o1, o1, q); }
        if (nb_ + 2 < n) { y[(size_t)(nb_ + 2) * 64 + c] = o2; s += o2; q = fmaf(o2, o2, q); }
        if (nb_ + 3 < n) { y[(size_t)(nb_ + 3) * 64 + c] = o3; s += o3; q = fmaf(o3, o3, q); }
    }
    __syncthreads();
    ls[t] = s; lq[t] = q;
    __syncthreads();
    if (t < 64) {
        float ss = ls[t] + ls[t + 64] + ls[t + 128] + ls[t + 192];
        float qq = lq[t] + lq[t + 64] + lq[t + 128] + lq[t + 192];
        atomicAdd(&sums_o[t], ss);
        atomicAdd(&sqs_o[t], qq);
    }
}

// ---------------- final: fused BN+ELU + dot(64) + 5*tanh ----------------

__global__ void final_k(const float* __restrict__ z, int n,
                        const float* __restrict__ sums, const float* __restrict__ sqs,
                        const float* __restrict__ g, const float* __restrict__ be,
                        const float* __restrict__ W2, const float* __restrict__ b2,
                        float* __restrict__ out) {
    int t = blockIdx.x * blockDim.x + threadIdx.x;
    int node = t >> 6, c = t & 63;
    if (node >= n) return;
    float inv_n = 1.f / n;
    float mu = sums[c] * inv_n;
    float var = sqs[c] * inv_n - mu * mu;
    float scc = rsqrtf(var + 1e-5f) * g[c];
    float sh = be[c] - mu * scc;
    float v = z[(size_t)node * 64 + c] * scc + sh;
    v = v > 0.f ? v : __expf(v) - 1.f;
    v *= W2[c];
    v += __shfl_xor(v, 1);
    v += __shfl_xor(v, 2);
    v += __shfl_xor(v, 4);
    v += __shfl_xor(v, 8);
    v += __shfl_xor(v, 16);
    v += __shfl_xor(v, 32);
    if (c == 0) out[node] = 5.0f * tanhf(v + b2[0]);
}

// ---------------- launch ----------------

extern "C" void kernel_launch(void* const* d_in, const int* in_sizes, int n_in,
                              void* d_out, int out_size, void* d_ws, size_t ws_size,
                              hipStream_t stream) {
    const float* x0    = (const float*)d_in[0];
    const int*   eidx  = (const int*)d_in[1];
    const float* eattr = (const float*)d_in[2];

    const float* Wl[2]; const float* bl[2]; const float* Wr[2]; const float* br[2];
    const float* We[2]; const float* att[2]; const float* g[2]; const float* be[2];
    for (int l = 0; l < 2; ++l) {
        int base = 3 + l * 9;
        Wl[l]  = (const float*)d_in[base + 0];
        bl[l]  = (const float*)d_in[base + 1];
        Wr[l]  = (const float*)d_in[base + 2];
        br[l]  = (const float*)d_in[base + 3];
        We[l]  = (const float*)d_in[base + 4];
        att[l] = (const float*)d_in[base + 5];
        // base+6 = bias: per-channel constant, cancels exactly under BatchNorm
        g[l]   = (const float*)d_in[base + 7];
        be[l]  = (const float*)d_in[base + 8];
    }
    const float* W1 = (const float*)d_in[21];
    const float* b1 = (const float*)d_in[22];
    const float* gf = (const float*)d_in[23];
    const float* bf = (const float*)d_in[24];
    const float* W2 = (const float*)d_in[25];
    const float* b2 = (const float*)d_in[26];

    const int N = in_sizes[0] / 128;
    const int E = in_sizes[1] / 2;
    const int* src = eidx;
    const int* dst = eidx + E;
    const int nbk = (N + 127) >> 7;
    const int nblkA = (E + 8191) / 8192;

    // workspace (4-byte units).  Region A shared: (tea,tsd) then (h0,h1).
    float* ws = (float*)d_ws;
    size_t o = 0;
    float* regionA = ws + o; o += (size_t)2 * N * HC;
    uint2* tea = (uint2*)regionA;
    uint*  tsd = (uint*)(regionA + (size_t)2 * E);
    float* h0  = regionA;
    float* h1  = regionA + (size_t)N * HC;
    uint2* eat_sorted = (uint2*)(ws + o); o += (size_t)E * 2;
    uint*  spre_sorted = (uint*)(ws + o);  o += (size_t)E;
    bf16*  xl  = (bf16*)(ws + o);  o += (size_t)N * 32;
    bf16*  xr  = (bf16*)(ws + o);  o += (size_t)N * 32;
    int*   row_start = (int*)(ws + o); o += (size_t)N + 1;
    int*   hist   = (int*)(ws + o); o += (size_t)nbk * nblkA + 64;
    float* stats  = ws + o; o += 6 * HC;
    int*   bstart = (int*)(ws + o); o += 513;
    int*   btot   = (int*)(ws + o); o += 512;
    float* s0 = stats,        *q0 = stats + 64;
    float* s1 = stats + 128,  *q1 = stats + 192;
    float* sf = stats + 256,  *qf = stats + 320;

    const int ngroups4  = (N + 3) / 4;
    const int ngroups16 = (N + 15) / 16;
    const int lin_grid = ngroups16 < 1024 ? ngroups16 : 1024;

    hipMemsetAsync(stats, 0, 6 * HC * 4, stream);

    // CSR build: atomic-free 3-pass radix with parallel scans (shared by both layers)
    histA_k<<<nblkA, 1024, 0, stream>>>(dst, hist, E, nbk, nblkA);
    scanB_k<<<nbk, 256, 0, stream>>>(hist, btot, nblkA);
    scanC_k<<<1, 512, 0, stream>>>(btot, bstart, nbk, E);
    bucketC_k<<<nblkA, 1024, 0, stream>>>(src, dst, (const float4*)eattr, hist, bstart,
                                          tsd, tea, E, nbk, nblkA);
    bucket_sort_k<<<nbk, 256, 0, stream>>>(tsd, tea, bstart, spre_sorted, eat_sorted,
                                           row_start, N);

    // layer 0
    lin128_k<<<lin_grid, 256, 0, stream>>>(x0, N, Wl[0], bl[0], Wr[0], br[0], xl, xr, ngroups16);
    gat_node_k<<<ngroups4, 256, 0, stream>>>(xl, xr, We[0], att[0], row_start,
                                             spre_sorted, eat_sorted, h0, N);
    bn_stats_k<<<256, 256, 0, stream>>>(h0, s0, q0, N);

    // layer 1 (input BN+ELU fused)
    lin64bn_k<<<lin_grid, 256, 0, stream>>>(h0, N, s0, q0, g[0], be[0],
                                            Wl[1], bl[1], Wr[1], br[1], xl, xr, ngroups16);
    gat_node_k<<<ngroups4, 256, 0, stream>>>(xl, xr, We[1], att[1], row_start,
                                             spre_sorted, eat_sorted, h1, N);
    bn_stats_k<<<256, 256, 0, stream>>>(h1, s1, q1, N);

    // head
    float* y = h0;  // h0 dead after lin64bn
    lin1_k<<<lin_grid, 256, 0, stream>>>(h1, N, s1, q1, g[1], be[1], W1, b1, y, sf, qf, ngroups16);
    final_k<<<(int)(((size_t)N * 64 + 255) / 256), 256, 0, stream>>>(
        y, N, sf, qf, gf, bf, W2, b2, (float*)d_out);
}